// Round 8
// baseline (180.848 us; speedup 1.0000x reference)
//
#include <hip/hip_runtime.h>

#define A_N 1024
#define T_N 256
#define CS 384
#define CZ 128
#define CA 128
#define CP 16
#define LN_EPS 1e-5f

typedef __bf16  bf16x8 __attribute__((ext_vector_type(8)));
typedef float   f32x4  __attribute__((ext_vector_type(4)));

#define WSTRIDE 136   // bf16 elements per wb row (272 B, 16B-aligned)
#define ZSTRIDE 132   // floats per staged zij row (528 B = 33 float4, 16B-aligned,
                      // 33 ≡ 1 mod 8 -> conflict-free b128 column reads)

// ============================================================================
// Kernel 1: token-space phase, 1280 blocks x 256 threads. (unchanged)
//   blocks [0,256):    s phase — Ys[t,:] = LN(s_trunk[t,:]) @ W_s (2-way K-split)
//   blocks [256,1280): z phase — 64 token-pair rows/block, LDS-staged zij,
//     padded-stride fragment reads, LN folded into MFMA epilogue; tok recovery.
// ============================================================================
__global__ __launch_bounds__(256) void token_kernel(
        const float* __restrict__ s_trunk,
        const float* __restrict__ gs,
        const float* __restrict__ bs,
        const float* __restrict__ W_s,
        float* __restrict__ Ys,
        const float* __restrict__ zij,
        const float* __restrict__ gz,
        const float* __restrict__ bz,
        const float* __restrict__ W_z,
        float* __restrict__ Yz,
        const float* __restrict__ a2t,
        int* __restrict__ tok) {
    __shared__ float  zs[64 * ZSTRIDE];     // 33 KB z staging / s-phase scratch
    __shared__ __bf16 wb[CP * WSTRIDE];     // wb[j][k] = bf16(gz[k]*W_z[k][j])
    __shared__ float2 gb_part[16][16];
    __shared__ float  Gw_sh[CP], Bw_sh[CP];

    int tid = threadIdx.x;

    if (blockIdx.x < 256) {
        // ------------------------- s phase -------------------------
        float*  xs    = zs;                    // [384]
        float2* sred2 = (float2*)(zs + 384);   // [4]
        float*  part  = zs + 392;              // [2][128]
        int t = blockIdx.x;
        float sum = 0.f, sq = 0.f;
        {
            float v = s_trunk[t * CS + tid];
            xs[tid] = v; sum = v; sq = v * v;
            if (tid < CS - 256) {              // tid < 128
                float v2 = s_trunk[t * CS + 256 + tid];
                xs[256 + tid] = v2; sum += v2; sq += v2 * v2;
            }
        }
        #pragma unroll
        for (int off = 32; off > 0; off >>= 1) {
            sum += __shfl_down(sum, off);
            sq  += __shfl_down(sq,  off);
        }
        if ((tid & 63) == 0) sred2[tid >> 6] = make_float2(sum, sq);
        __syncthreads();
        float s_ = sred2[0].x + sred2[1].x + sred2[2].x + sred2[3].x;
        float ss = sred2[0].y + sred2[1].y + sred2[2].y + sred2[3].y;
        float m = s_ * (1.f / CS);
        float rstd = rsqrtf(ss * (1.f / CS) - m * m + LN_EPS);

        int col = tid & 127, seg = tid >> 7;   // 2 segs x 192 k's
        float a0 = 0.f, a1 = 0.f, a2 = 0.f, a3 = 0.f;
        int k0 = seg * (CS / 2);
        for (int k = k0; k < k0 + CS / 2; k += 4) {
            float z0 = (xs[k + 0] - m) * rstd * gs[k + 0] + bs[k + 0];
            float z1 = (xs[k + 1] - m) * rstd * gs[k + 1] + bs[k + 1];
            float z2 = (xs[k + 2] - m) * rstd * gs[k + 2] + bs[k + 2];
            float z3 = (xs[k + 3] - m) * rstd * gs[k + 3] + bs[k + 3];
            a0 = fmaf(z0, W_s[(k + 0) * CA + col], a0);
            a1 = fmaf(z1, W_s[(k + 1) * CA + col], a1);
            a2 = fmaf(z2, W_s[(k + 2) * CA + col], a2);
            a3 = fmaf(z3, W_s[(k + 3) * CA + col], a3);
        }
        part[seg * 128 + col] = (a0 + a1) + (a2 + a3);
        __syncthreads();
        if (tid < 128) Ys[t * CA + tid] = part[tid] + part[128 + tid];
        return;
    }

    // ------------------------- z phase (+ tok) -------------------------
    int b = blockIdx.x - 256;

    // tok recovery: block b scans one-hot row a2t[b,:] (1 KB, coalesced)
    { float v = a2t[(size_t)b * T_N + tid]; if (v > 0.5f) tok[b] = tid; }

    // stage Wg^T (bf16) + Gw/Bw partials
    {
        int j = tid & 15, seg = tid >> 4;       // 16 segs x 8 k's
        float sg = 0.f, sb = 0.f;
        #pragma unroll
        for (int i = 0; i < 8; ++i) {
            int k = seg * 8 + i;
            float w = W_z[k * CP + j];
            float gw = gz[k] * w;
            wb[j * WSTRIDE + k] = (__bf16)gw;
            sg += gw;
            sb = fmaf(bz[k], w, sb);
        }
        gb_part[seg][j] = make_float2(sg, sb);
    }

    // stage 64 zij rows, fully coalesced (32 KB contiguous per block)
    size_t R0 = (size_t)b * 64;
    const float4* zg = (const float4*)(zij + R0 * CZ);
    #pragma unroll
    for (int it = 0; it < 8; ++it) {
        int g = it * 256 + tid;
        int row = g >> 5, c4 = g & 31;
        *(float4*)&zs[row * ZSTRIDE + c4 * 4] = zg[g];
    }
    __syncthreads();                            // zs, wb, gb_part ready

    if (tid < CP) {
        float sg = 0.f, sb = 0.f;
        #pragma unroll
        for (int s = 0; s < 16; ++s) { float2 p = gb_part[s][tid]; sg += p.x; sb += p.y; }
        Gw_sh[tid] = sg; Bw_sh[tid] = sb;
    }

    int wave = tid >> 6, lane = tid & 63;
    int m16  = lane & 15, quad = lane >> 4;
    int r_loc = wave * 16 + m16;                // local row this lane owns

    // fragment reads from LDS (stride 33 float4 -> conflict-free columns)
    float4 xv[8];
    #pragma unroll
    for (int s = 0; s < 4; ++s) {
        xv[2 * s]     = *(const float4*)&zs[r_loc * ZSTRIDE + quad * 8 + 32 * s];
        xv[2 * s + 1] = *(const float4*)&zs[r_loc * ZSTRIDE + quad * 8 + 32 * s + 4];
    }

    float zsum = 0.f, zsq = 0.f;
    #pragma unroll
    for (int i = 0; i < 8; ++i) {
        float4 v = xv[i];
        zsum += (v.x + v.y) + (v.z + v.w);
        zsq  += v.x * v.x + v.y * v.y + v.z * v.z + v.w * v.w;
    }
    zsum += __shfl_xor(zsum, 16);  zsq += __shfl_xor(zsq, 16);
    zsum += __shfl_xor(zsum, 32);  zsq += __shfl_xor(zsq, 32);
    float mval = zsum * (1.f / CZ);
    float rstd = rsqrtf(zsq * (1.f / CZ) - mval * mval + LN_EPS);

    __syncthreads();                            // Gw/Bw ready

    f32x4 acc = {0.f, 0.f, 0.f, 0.f};
    #pragma unroll
    for (int s = 0; s < 4; ++s) {
        float4 v0 = xv[2 * s], v1 = xv[2 * s + 1];
        bf16x8 af;
        af[0] = (__bf16)v0.x; af[1] = (__bf16)v0.y;
        af[2] = (__bf16)v0.z; af[3] = (__bf16)v0.w;
        af[4] = (__bf16)v1.x; af[5] = (__bf16)v1.y;
        af[6] = (__bf16)v1.z; af[7] = (__bf16)v1.w;
        bf16x8 bfv = *(const bf16x8*)&wb[m16 * WSTRIDE + quad * 8 + 32 * s];
        acc = __builtin_amdgcn_mfma_f32_16x16x32_bf16(af, bfv, acc, 0, 0, 0);
    }

    // epilogue: C layout row = quad*4+i, col = m16
    float gwj = Gw_sh[m16], bwj = Bw_sh[m16];
    size_t obase = R0 + wave * 16;
    #pragma unroll
    for (int i = 0; i < 4; ++i) {
        int r = quad * 4 + i;
        float mi = __shfl(mval, r);             // stats live in lane r (lane&15==r)
        float ri = __shfl(rstd, r);
        float y = ri * (acc[i] - mi * gwj) + bwj;
        Yz[(obase + r) * CP + m16] = y;
    }
}

// ============================================================================
// Kernel 2: per-atom output, 2048 blocks x 256 threads (half row each).
// R7's per-use asm pins FAILED to stop load-sinking (load i+1 can still sink
// below pin i — nothing orders them). This version: 8 loads into NAMED
// registers (no array -> no scratch), then ONE sched_barrier(0) — a hard
// scheduling fence nothing may cross — then the process loop. Loads stay
// issued 8-deep; first-use waits become progressive vmcnt(N).
// ============================================================================
#define PLM_STEP(PF, I)                                                    \
    {                                                                      \
        int f4 = base + (I) * 256;                                         \
        int tb = tok_sh[f4 >> 2];                                          \
        int x  = tb * 4 + (f4 & 3);                                        \
        float4 yv = yz_sh[x ^ ((x >> 3) & 7)];                             \
        float4 o;                                                          \
        o.x = PF.x + yv.x; o.y = PF.y + yv.y;                              \
        o.z = PF.z + yv.z; o.w = PF.w + yv.w;                              \
        orow[f4] = o;                                                      \
    }

__global__ __launch_bounds__(256, 6) void atom_plm_kernel(
        const float* __restrict__ plm,
        const float* __restrict__ Yz,
        const int* __restrict__ tok,
        const float* __restrict__ cl,
        const float* __restrict__ ql,
        const float* __restrict__ rl,
        const float* __restrict__ Ys,
        const float* __restrict__ W_r,
        float* __restrict__ out_cl,
        float* __restrict__ out_plm,
        float* __restrict__ out_ql) {
    __shared__ int    tok_sh[A_N];                 // 4 KB
    __shared__ float4 yz_sh[T_N * CP / 4];         // 16 KB, swizzled

    int bid  = blockIdx.x;
    int a    = bid >> 1;
    int half = bid & 1;                            // which half of the plm row
    int tid  = threadIdx.x;
    int ta   = tok[a];                             // block-uniform

    ((int4*)tok_sh)[tid] = ((const int4*)tok)[tid];     // 1024 ints, 256 int4

    const float4* yrow = (const float4*)(Yz + (size_t)ta * (T_N * CP));
    #pragma unroll
    for (int p = 0; p < 4; ++p) {
        int j = p * 256 + tid;
        yz_sh[j ^ ((j >> 3) & 7)] = yrow[j];
    }

    // cl / ql (only half 0; independent of LDS)
    if (half == 0) {
        if (tid < 128) {
            out_cl[(size_t)a * CA + tid] = cl[(size_t)a * CA + tid]
                                         + Ys[(size_t)ta * CA + tid];
        } else {
            int c = tid - 128;
            float r0 = rl[a * 3 + 0], r1 = rl[a * 3 + 1], r2 = rl[a * 3 + 2];
            out_ql[(size_t)a * CA + c] = ql[(size_t)a * CA + c]
                + fmaf(r0, W_r[c], fmaf(r1, W_r[CA + c], r2 * W_r[2 * CA + c]));
        }
    }
    __syncthreads();                               // yz_sh/tok_sh ready

    const float4* prow = (const float4*)(plm     + (size_t)a * (A_N * CP));
    float4*       orow = (float4*)      (out_plm + (size_t)a * (A_N * CP));
    int base = half * 2048 + tid;                  // this block's float4 range

    // issue ALL 8 loads back-to-back into named regs (8-deep, 128 B/thread)
    float4 p0 = prow[base +    0];
    float4 p1 = prow[base +  256];
    float4 p2 = prow[base +  512];
    float4 p3 = prow[base +  768];
    float4 p4 = prow[base + 1024];
    float4 p5 = prow[base + 1280];
    float4 p6 = prow[base + 1536];
    float4 p7 = prow[base + 1792];
    __builtin_amdgcn_sched_barrier(0);             // nothing crosses: loads stay up

    PLM_STEP(p0, 0); PLM_STEP(p1, 1); PLM_STEP(p2, 2); PLM_STEP(p3, 3);
    PLM_STEP(p4, 4); PLM_STEP(p5, 5); PLM_STEP(p6, 6); PLM_STEP(p7, 7);
}

extern "C" void kernel_launch(void* const* d_in, const int* in_sizes, int n_in,
                              void* d_out, int out_size, void* d_ws, size_t ws_size,
                              hipStream_t stream) {
    const float* a2t     = (const float*)d_in[0];
    const float* cl      = (const float*)d_in[1];
    const float* plm     = (const float*)d_in[2];
    const float* ql      = (const float*)d_in[3];
    const float* s_trunk = (const float*)d_in[4];
    const float* zij     = (const float*)d_in[5];
    const float* rl      = (const float*)d_in[6];
    const float* ln_s_g  = (const float*)d_in[7];
    const float* ln_s_b  = (const float*)d_in[8];
    const float* W_s     = (const float*)d_in[9];
    const float* ln_z_g  = (const float*)d_in[10];
    const float* ln_z_b  = (const float*)d_in[11];
    const float* W_z     = (const float*)d_in[12];
    const float* W_r     = (const float*)d_in[13];

    // workspace layout
    int*   tok = (int*)d_ws;                            // 4 KB
    float* Ys  = (float*)((char*)d_ws + 4096);          // 256*128 floats (128 KB)
    float* Yz  = (float*)((char*)d_ws + 4096 + 131072); // 65536*16 floats (4 MB)

    // output layout: cl [1024*128], plm [1024*1024*16], ql [1024*128]
    float* out_cl  = (float*)d_out;
    float* out_plm = out_cl + A_N * CA;
    float* out_ql  = out_plm + (size_t)A_N * A_N * CP;

    token_kernel<<<256 + T_N * T_N / 64, 256, 0, stream>>>(
        s_trunk, ln_s_g, ln_s_b, W_s, Ys,
        zij, ln_z_g, ln_z_b, W_z, Yz,
        a2t, tok);
    atom_plm_kernel<<<2 * A_N, 256, 0, stream>>>(
        plm, Yz, tok, cl, ql, rl, Ys, W_r,
        out_cl, out_plm, out_ql);
}

// Round 10
// 175.785 us; speedup vs baseline: 1.0288x; 1.0288x over previous
//
#include <hip/hip_runtime.h>

#define A_N 1024
#define T_N 256
#define CS 384
#define CZ 128
#define CA 128
#define CP 16
#define LN_EPS 1e-5f

typedef __bf16  bf16x8 __attribute__((ext_vector_type(8)));
typedef float   f32x4  __attribute__((ext_vector_type(4)));

#define WSTRIDE 136   // bf16 elements per wb row (272 B, 16B-aligned)
#define ZSTRIDE 132   // floats per staged zij row (528 B = 33 float4, 16B-aligned,
                      // 33 ≡ 1 mod 8 -> conflict-free b128 column reads)

// ============================================================================
// Kernel 1: token-space phase, 1280 blocks x 256 threads. (unchanged)
//   blocks [0,256):    s phase — Ys[t,:] = LN(s_trunk[t,:]) @ W_s (2-way K-split)
//   blocks [256,1280): z phase — 64 token-pair rows/block, LDS-staged zij,
//     padded-stride fragment reads, LN folded into MFMA epilogue; tok recovery.
// ============================================================================
__global__ __launch_bounds__(256) void token_kernel(
        const float* __restrict__ s_trunk,
        const float* __restrict__ gs,
        const float* __restrict__ bs,
        const float* __restrict__ W_s,
        float* __restrict__ Ys,
        const float* __restrict__ zij,
        const float* __restrict__ gz,
        const float* __restrict__ bz,
        const float* __restrict__ W_z,
        float* __restrict__ Yz,
        const float* __restrict__ a2t,
        int* __restrict__ tok) {
    __shared__ float  zs[64 * ZSTRIDE];     // 33 KB z staging / s-phase scratch
    __shared__ __bf16 wb[CP * WSTRIDE];     // wb[j][k] = bf16(gz[k]*W_z[k][j])
    __shared__ float2 gb_part[16][16];
    __shared__ float  Gw_sh[CP], Bw_sh[CP];

    int tid = threadIdx.x;

    if (blockIdx.x < 256) {
        // ------------------------- s phase -------------------------
        float*  xs    = zs;                    // [384]
        float2* sred2 = (float2*)(zs + 384);   // [4]
        float*  part  = zs + 392;              // [2][128]
        int t = blockIdx.x;
        float sum = 0.f, sq = 0.f;
        {
            float v = s_trunk[t * CS + tid];
            xs[tid] = v; sum = v; sq = v * v;
            if (tid < CS - 256) {              // tid < 128
                float v2 = s_trunk[t * CS + 256 + tid];
                xs[256 + tid] = v2; sum += v2; sq += v2 * v2;
            }
        }
        #pragma unroll
        for (int off = 32; off > 0; off >>= 1) {
            sum += __shfl_down(sum, off);
            sq  += __shfl_down(sq,  off);
        }
        if ((tid & 63) == 0) sred2[tid >> 6] = make_float2(sum, sq);
        __syncthreads();
        float s_ = sred2[0].x + sred2[1].x + sred2[2].x + sred2[3].x;
        float ss = sred2[0].y + sred2[1].y + sred2[2].y + sred2[3].y;
        float m = s_ * (1.f / CS);
        float rstd = rsqrtf(ss * (1.f / CS) - m * m + LN_EPS);

        int col = tid & 127, seg = tid >> 7;   // 2 segs x 192 k's
        float a0 = 0.f, a1 = 0.f, a2 = 0.f, a3 = 0.f;
        int k0 = seg * (CS / 2);
        for (int k = k0; k < k0 + CS / 2; k += 4) {
            float z0 = (xs[k + 0] - m) * rstd * gs[k + 0] + bs[k + 0];
            float z1 = (xs[k + 1] - m) * rstd * gs[k + 1] + bs[k + 1];
            float z2 = (xs[k + 2] - m) * rstd * gs[k + 2] + bs[k + 2];
            float z3 = (xs[k + 3] - m) * rstd * gs[k + 3] + bs[k + 3];
            a0 = fmaf(z0, W_s[(k + 0) * CA + col], a0);
            a1 = fmaf(z1, W_s[(k + 1) * CA + col], a1);
            a2 = fmaf(z2, W_s[(k + 2) * CA + col], a2);
            a3 = fmaf(z3, W_s[(k + 3) * CA + col], a3);
        }
        part[seg * 128 + col] = (a0 + a1) + (a2 + a3);
        __syncthreads();
        if (tid < 128) Ys[t * CA + tid] = part[tid] + part[128 + tid];
        return;
    }

    // ------------------------- z phase (+ tok) -------------------------
    int b = blockIdx.x - 256;

    // tok recovery: block b scans one-hot row a2t[b,:] (1 KB, coalesced)
    { float v = a2t[(size_t)b * T_N + tid]; if (v > 0.5f) tok[b] = tid; }

    // stage Wg^T (bf16) + Gw/Bw partials
    {
        int j = tid & 15, seg = tid >> 4;       // 16 segs x 8 k's
        float sg = 0.f, sb = 0.f;
        #pragma unroll
        for (int i = 0; i < 8; ++i) {
            int k = seg * 8 + i;
            float w = W_z[k * CP + j];
            float gw = gz[k] * w;
            wb[j * WSTRIDE + k] = (__bf16)gw;
            sg += gw;
            sb = fmaf(bz[k], w, sb);
        }
        gb_part[seg][j] = make_float2(sg, sb);
    }

    // stage 64 zij rows, fully coalesced (32 KB contiguous per block)
    size_t R0 = (size_t)b * 64;
    const float4* zg = (const float4*)(zij + R0 * CZ);
    #pragma unroll
    for (int it = 0; it < 8; ++it) {
        int g = it * 256 + tid;
        int row = g >> 5, c4 = g & 31;
        *(float4*)&zs[row * ZSTRIDE + c4 * 4] = zg[g];
    }
    __syncthreads();                            // zs, wb, gb_part ready

    if (tid < CP) {
        float sg = 0.f, sb = 0.f;
        #pragma unroll
        for (int s = 0; s < 16; ++s) { float2 p = gb_part[s][tid]; sg += p.x; sb += p.y; }
        Gw_sh[tid] = sg; Bw_sh[tid] = sb;
    }

    int wave = tid >> 6, lane = tid & 63;
    int m16  = lane & 15, quad = lane >> 4;
    int r_loc = wave * 16 + m16;                // local row this lane owns

    // fragment reads from LDS (stride 33 float4 -> conflict-free columns)
    float4 xv[8];
    #pragma unroll
    for (int s = 0; s < 4; ++s) {
        xv[2 * s]     = *(const float4*)&zs[r_loc * ZSTRIDE + quad * 8 + 32 * s];
        xv[2 * s + 1] = *(const float4*)&zs[r_loc * ZSTRIDE + quad * 8 + 32 * s + 4];
    }

    float zsum = 0.f, zsq = 0.f;
    #pragma unroll
    for (int i = 0; i < 8; ++i) {
        float4 v = xv[i];
        zsum += (v.x + v.y) + (v.z + v.w);
        zsq  += v.x * v.x + v.y * v.y + v.z * v.z + v.w * v.w;
    }
    zsum += __shfl_xor(zsum, 16);  zsq += __shfl_xor(zsq, 16);
    zsum += __shfl_xor(zsum, 32);  zsq += __shfl_xor(zsq, 32);
    float mval = zsum * (1.f / CZ);
    float rstd = rsqrtf(zsq * (1.f / CZ) - mval * mval + LN_EPS);

    __syncthreads();                            // Gw/Bw ready

    f32x4 acc = {0.f, 0.f, 0.f, 0.f};
    #pragma unroll
    for (int s = 0; s < 4; ++s) {
        float4 v0 = xv[2 * s], v1 = xv[2 * s + 1];
        bf16x8 af;
        af[0] = (__bf16)v0.x; af[1] = (__bf16)v0.y;
        af[2] = (__bf16)v0.z; af[3] = (__bf16)v0.w;
        af[4] = (__bf16)v1.x; af[5] = (__bf16)v1.y;
        af[6] = (__bf16)v1.z; af[7] = (__bf16)v1.w;
        bf16x8 bfv = *(const bf16x8*)&wb[m16 * WSTRIDE + quad * 8 + 32 * s];
        acc = __builtin_amdgcn_mfma_f32_16x16x32_bf16(af, bfv, acc, 0, 0, 0);
    }

    // epilogue: C layout row = quad*4+i, col = m16
    float gwj = Gw_sh[m16], bwj = Bw_sh[m16];
    size_t obase = R0 + wave * 16;
    #pragma unroll
    for (int i = 0; i < 4; ++i) {
        int r = quad * 4 + i;
        float mi = __shfl(mval, r);             // stats live in lane r (lane&15==r)
        float ri = __shfl(rstd, r);
        float y = ri * (acc[i] - mi * gwj) + bwj;
        Yz[(obase + r) * CP + m16] = y;
    }
}

// ============================================================================
// Kernel 2: per-atom output, 2048 blocks x 256 threads (half row each).
// R6-R8: issue depth does NOT move the 40us / 2.7 TB/s plateau. Theory now:
// write-allocate pollution — the 64 MB out_plm store stream allocates L2/L3
// lines and fights the plm read stream. Fix: nontemporal (nt) loads for plm
// + nt stores for out_plm, via ext_vector f32x4 (the HIP float4 type is
// rejected by the builtin — that was R9's compile error). Yz/tok staging
// keeps cached loads.
// ============================================================================
#define PLM_STEP(PF, I)                                                    \
    {                                                                      \
        int f4 = base + (I) * 256;                                         \
        int tb = tok_sh[f4 >> 2];                                          \
        int x  = tb * 4 + (f4 & 3);                                        \
        float4 yv = yz_sh[x ^ ((x >> 3) & 7)];                             \
        f32x4 o;                                                           \
        o[0] = PF[0] + yv.x; o[1] = PF[1] + yv.y;                          \
        o[2] = PF[2] + yv.z; o[3] = PF[3] + yv.w;                          \
        __builtin_nontemporal_store(o, &orow[f4]);                         \
    }

__global__ __launch_bounds__(256, 6) void atom_plm_kernel(
        const float* __restrict__ plm,
        const float* __restrict__ Yz,
        const int* __restrict__ tok,
        const float* __restrict__ cl,
        const float* __restrict__ ql,
        const float* __restrict__ rl,
        const float* __restrict__ Ys,
        const float* __restrict__ W_r,
        float* __restrict__ out_cl,
        float* __restrict__ out_plm,
        float* __restrict__ out_ql) {
    __shared__ int    tok_sh[A_N];                 // 4 KB
    __shared__ float4 yz_sh[T_N * CP / 4];         // 16 KB, swizzled

    int bid  = blockIdx.x;
    int a    = bid >> 1;
    int half = bid & 1;                            // which half of the plm row
    int tid  = threadIdx.x;
    int ta   = tok[a];                             // block-uniform

    ((int4*)tok_sh)[tid] = ((const int4*)tok)[tid];     // 1024 ints, 256 int4

    const float4* yrow = (const float4*)(Yz + (size_t)ta * (T_N * CP));
    #pragma unroll
    for (int p = 0; p < 4; ++p) {
        int j = p * 256 + tid;
        yz_sh[j ^ ((j >> 3) & 7)] = yrow[j];
    }

    // cl / ql (only half 0; independent of LDS)
    if (half == 0) {
        if (tid < 128) {
            out_cl[(size_t)a * CA + tid] = cl[(size_t)a * CA + tid]
                                         + Ys[(size_t)ta * CA + tid];
        } else {
            int c = tid - 128;
            float r0 = rl[a * 3 + 0], r1 = rl[a * 3 + 1], r2 = rl[a * 3 + 2];
            out_ql[(size_t)a * CA + c] = ql[(size_t)a * CA + c]
                + fmaf(r0, W_r[c], fmaf(r1, W_r[CA + c], r2 * W_r[2 * CA + c]));
        }
    }
    __syncthreads();                               // yz_sh/tok_sh ready

    const f32x4* prow = (const f32x4*)(plm     + (size_t)a * (A_N * CP));
    f32x4*       orow = (f32x4*)      (out_plm + (size_t)a * (A_N * CP));
    int base = half * 2048 + tid;                  // this block's float4 range

    // issue ALL 8 loads back-to-back into named regs (8-deep, 128 B/thread)
    // nontemporal: streaming read, no L2/L3 allocation
    f32x4 p0 = __builtin_nontemporal_load(&prow[base +    0]);
    f32x4 p1 = __builtin_nontemporal_load(&prow[base +  256]);
    f32x4 p2 = __builtin_nontemporal_load(&prow[base +  512]);
    f32x4 p3 = __builtin_nontemporal_load(&prow[base +  768]);
    f32x4 p4 = __builtin_nontemporal_load(&prow[base + 1024]);
    f32x4 p5 = __builtin_nontemporal_load(&prow[base + 1280]);
    f32x4 p6 = __builtin_nontemporal_load(&prow[base + 1536]);
    f32x4 p7 = __builtin_nontemporal_load(&prow[base + 1792]);
    __builtin_amdgcn_sched_barrier(0);             // loads stay issued 8-deep

    PLM_STEP(p0, 0); PLM_STEP(p1, 1); PLM_STEP(p2, 2); PLM_STEP(p3, 3);
    PLM_STEP(p4, 4); PLM_STEP(p5, 5); PLM_STEP(p6, 6); PLM_STEP(p7, 7);
}

extern "C" void kernel_launch(void* const* d_in, const int* in_sizes, int n_in,
                              void* d_out, int out_size, void* d_ws, size_t ws_size,
                              hipStream_t stream) {
    const float* a2t     = (const float*)d_in[0];
    const float* cl      = (const float*)d_in[1];
    const float* plm     = (const float*)d_in[2];
    const float* ql      = (const float*)d_in[3];
    const float* s_trunk = (const float*)d_in[4];
    const float* zij     = (const float*)d_in[5];
    const float* rl      = (const float*)d_in[6];
    const float* ln_s_g  = (const float*)d_in[7];
    const float* ln_s_b  = (const float*)d_in[8];
    const float* W_s     = (const float*)d_in[9];
    const float* ln_z_g  = (const float*)d_in[10];
    const float* ln_z_b  = (const float*)d_in[11];
    const float* W_z     = (const float*)d_in[12];
    const float* W_r     = (const float*)d_in[13];

    // workspace layout
    int*   tok = (int*)d_ws;                            // 4 KB
    float* Ys  = (float*)((char*)d_ws + 4096);          // 256*128 floats (128 KB)
    float* Yz  = (float*)((char*)d_ws + 4096 + 131072); // 65536*16 floats (4 MB)

    // output layout: cl [1024*128], plm [1024*1024*16], ql [1024*128]
    float* out_cl  = (float*)d_out;
    float* out_plm = out_cl + A_N * CA;
    float* out_ql  = out_plm + (size_t)A_N * A_N * CP;

    token_kernel<<<256 + T_N * T_N / 64, 256, 0, stream>>>(
        s_trunk, ln_s_g, ln_s_b, W_s, Ys,
        zij, ln_z_g, ln_z_b, W_z, Yz,
        a2t, tok);
    atom_plm_kernel<<<2 * A_N, 256, 0, stream>>>(
        plm, Yz, tok, cl, ql, rl, Ys, W_r,
        out_cl, out_plm, out_ql);
}